// Round 4
// baseline (1378.447 us; speedup 1.0000x reference)
//
#include <hip/hip_runtime.h>

// Problem: bs=8, seq=16, hw=32*32=1024, ck=256, cv=3, steps=seq-1=15
// Inputs fp32 (confirmed round 3): k[8][16][1024][256], v[8][16][1024][3],
//                                  attention[8][16][1024], seq_mask int32[8][16]
// Outputs fp32: out_v[8][15][1024][3] ++ gt[8][15][1024][3]
// Numerics: m_k EMA state kept fp32 (matches np); MFMA inputs rounded to fp16
// (2^-12/elem -> ~3e-3 logit noise, 8x better than bf16 which gave 3.1e-2).
#define BS 8
#define SEQ 16
#define HW 1024
#define CK 256
#define CV 3
#define STEPS 15

#define BQ 32          // q-rows per block
#define BP 32          // key rows per p-tile
#define SKP 264        // padded fp16 row stride (256+8)
#define SSP 33         // padded fp32 stride for S tiles

typedef unsigned short u16;
typedef _Float16 half8 __attribute__((ext_vector_type(8)));  // MFMA A/B frag (4 VGPRs)
typedef short short8 __attribute__((ext_vector_type(8)));
typedef float floatx4 __attribute__((ext_vector_type(4)));   // MFMA C/D frag

__device__ __forceinline__ u16 f2h(float f) {   // fp32 -> fp16 RTN-even
  _Float16 h = (_Float16)f;
  return __builtin_bit_cast(unsigned short, h);
}

// convert 8 consecutive fp32 at src to 8 packed fp16 at dst (16B)
__device__ __forceinline__ void cvt8(const float* __restrict__ src, u16* dst) {
  float4 a = *(const float4*)src;
  float4 b = *(const float4*)(src + 4);
  u16 t[8] = {f2h(a.x), f2h(a.y), f2h(a.z), f2h(a.w),
              f2h(b.x), f2h(b.y), f2h(b.z), f2h(b.w)};
  *(int4*)dst = *(const int4*)t;
}

// ---- per-pass init: m_k(fp32)=0, m_v=0, pv = v[b0+lb, 0] ----
__global__ __launch_bounds__(256) void init_state(const float* __restrict__ v,
                                                  float* __restrict__ m_k,
                                                  float* __restrict__ m_v,
                                                  float* __restrict__ pv,
                                                  int b0, int nb) {
  int idx = blockIdx.x * 256 + threadIdx.x;
  const int stride = gridDim.x * 256;
  const int n_chunks = nb * HW * CK / 4;          // float4 chunks of m_k
  float4 zero4 = {0.f, 0.f, 0.f, 0.f};
  for (int i = idx; i < n_chunks; i += stride) ((float4*)m_k)[i] = zero4;
  const int n_v = nb * HW * CV;
  for (int i = idx; i < n_v; i += stride) {
    m_v[i] = 0.0f;
    int lb = i / (HW * CV);
    int r = i - lb * (HW * CV);
    pv[i] = v[(long)(b0 + lb) * SEQ * HW * CV + r];   // v[b][0][...]
  }
}

// ---------------- gt = v[:,1:] (pure copy) ----------------
__global__ __launch_bounds__(256) void gt_copy(const float* __restrict__ v,
                                               float* __restrict__ out) {
  int idx = blockIdx.x * 256 + threadIdx.x;
  const int n = BS * STEPS * HW * CV;            // 368,640
  if (idx >= n) return;
  int b = idx / (STEPS * HW * CV);
  int r = idx - b * (STEPS * HW * CV);
  int i = r / (HW * CV);
  int rr = r - i * (HW * CV);
  out[n + idx] = v[(long)(b * SEQ + i + 1) * (HW * CV) + rr];
}

// --------- per-step EMA update: m_k fp32 (+fp16 mirror m_kh), m_v fp32 ---------
// grid (nb,32), 256 thr: thread (pl=tid>>3, s=tid&7) does row pb*32+pl, cols [s*32,s*32+32)
__global__ __launch_bounds__(256) void update_state(
    const float* __restrict__ k, const float* __restrict__ att,
    const float* __restrict__ pv_in,
    float* __restrict__ m_k, u16* __restrict__ m_kh,
    float* __restrict__ m_v, int step, int b0)
{
  const int lb = blockIdx.x, b = b0 + lb, pb = blockIdx.y;
  const int tid = threadIdx.x;
  const int pl = tid >> 3, s = tid & 7;
  const int p = pb * 32 + pl;

  float a = att[(long)(b * SEQ + step) * HW + p];
  float g = 1.0f / (1.0f + __expf(-a));
  float og = 1.0f - g;

  const float* krow = k + ((long)(b * SEQ + step) * HW + p) * CK + s * 32;
  float* mrow  = m_k  + ((long)lb * HW + p) * CK + s * 32;
  u16*   mhrow = m_kh + ((long)lb * HW + p) * CK + s * 32;

  #pragma unroll
  for (int c = 0; c < 32; c += 8) {
    float kv[8], mo[8], nv[8];
    *(float4*)&kv[0] = *(const float4*)(krow + c);
    *(float4*)&kv[4] = *(const float4*)(krow + c + 4);
    *(float4*)&mo[0] = *(const float4*)(mrow + c);
    *(float4*)&mo[4] = *(const float4*)(mrow + c + 4);
    u16 nh[8];
    #pragma unroll
    for (int j = 0; j < 8; ++j) {
      nv[j] = fmaf(g, kv[j], og * mo[j]);
      nh[j] = f2h(nv[j]);
    }
    *(float4*)(mrow + c)     = *(const float4*)&nv[0];
    *(float4*)(mrow + c + 4) = *(const float4*)&nv[4];
    *(int4*)(mhrow + c)      = *(const int4*)&nh[0];
  }

  if (s == 0) {  // m_v = g*prev_v + (1-g)*m_v
    long base = ((long)lb * HW + p) * CV;
    #pragma unroll
    for (int c = 0; c < CV; ++c)
      m_v[base + c] = fmaf(g, pv_in[base + c], og * m_v[base + c]);
  }
}

// --------- per-step fused dual-attention (flash-style online softmax) ---------
// grid (nb, 32): block = (batch b0+lb, q-rows [q0, q0+32)). 256 thr = 4 waves.
// wave w: matrix mat=w>>1 (0: sim_k vs Kp, 1: sim_m vs Mp), p-subtile pi=w&1.
__global__ __launch_bounds__(256) void attn_step(
    const float* __restrict__ k, const float* __restrict__ v,
    const int* __restrict__ seq_mask,
    const u16* __restrict__ m_kh, const float* __restrict__ m_v,
    const float* __restrict__ pv_in, float* __restrict__ pv_out,
    float* __restrict__ out, int step, int b0)
{
  __shared__ u16  Kq[BQ * SKP];   // K_{i+1} q-tile (fp16)
  __shared__ u16  Kp[BP * SKP];   // K_i p-tile (fp16)
  __shared__ u16  Mp[BP * SKP];   // m_k p-tile (fp16)
  __shared__ float Sk[BQ * SSP];  // logits tiles
  __shared__ float Sm[BQ * SSP];
  __shared__ float PVt[BP * CV];  // prev_v p-tile
  __shared__ float MVt[BP * CV];  // m_v p-tile

  const int lb = blockIdx.x, b = b0 + lb;
  const int q0 = blockIdx.y * BQ;
  const int tid = threadIdx.x;
  const int wave = tid >> 6;
  const int lane = tid & 63;

  const float* Kn = k + (long)(b * SEQ + step + 1) * HW * CK;
  const float* Kc = k + (long)(b * SEQ + step) * HW * CK;
  const u16* Mb = m_kh + (long)lb * HW * CK;

  { // stage q-tile: thread (row=tid>>3, seg=tid&7) converts 32 floats
    int row = tid >> 3, seg = tid & 7;
    #pragma unroll
    for (int j = 0; j < 4; ++j)
      cvt8(Kn + (long)(q0 + row) * CK + seg * 32 + j * 8,
           &Kq[row * SKP + seg * 32 + j * 8]);
  }
  __syncthreads();

  // A-fragments in registers: lane holds A[m=lane&15][k=(lane>>4)*8 + j]
  half8 afrag[2][8];
  {
    const int r = lane & 15, kq = lane >> 4;
    #pragma unroll
    for (int qi = 0; qi < 2; ++qi)
      #pragma unroll
      for (int kk = 0; kk < 8; ++kk)
        afrag[qi][kk] = __builtin_bit_cast(half8,
            *(const short8*)&Kq[(qi * 16 + r) * SKP + kk * 32 + kq * 8]);
  }

  float mx0 = -1e30f, mx1 = -1e30f, l0 = 0.f, l1 = 0.f;
  float a00 = 0.f, a01 = 0.f, a02 = 0.f, a10 = 0.f, a11 = 0.f, a12 = 0.f;
  const int qrow = tid >> 3;   // 0..31
  const int s8 = tid & 7;      // p-subset: p_local in [s8*4, s8*4+4)

  const int mat = wave >> 1, pi = wave & 1;
  const u16* Bbase = mat ? Mp : Kp;
  float* Sbase = mat ? Sm : Sk;

  for (int pt = 0; pt < HW / BP; ++pt) {
    const int p0 = pt * BP;
    __syncthreads();  // previous iteration's S/PVt reads done before overwrite
    {
      int row = tid >> 3, seg = tid & 7;
      #pragma unroll
      for (int j = 0; j < 4; ++j) {
        cvt8(Kc + (long)(p0 + row) * CK + seg * 32 + j * 8,
             &Kp[row * SKP + seg * 32 + j * 8]);
        *(int4*)&Mp[row * SKP + seg * 32 + j * 8] =
            *(const int4*)(Mb + (long)(p0 + row) * CK + seg * 32 + j * 8);
      }
    }
    if (tid < BP * CV) {
      PVt[tid] = pv_in[((long)lb * HW + p0) * CV + tid];
      MVt[tid] = m_v[((long)lb * HW + p0) * CV + tid];
    }
    __syncthreads();

    // logits tile via fp16 MFMA (fp32 accumulate)
    floatx4 c0 = {0.f, 0.f, 0.f, 0.f}, c1 = {0.f, 0.f, 0.f, 0.f};
    {
      const int r = lane & 15, kq = lane >> 4;
      #pragma unroll
      for (int kk = 0; kk < 8; ++kk) {
        half8 bfrag = __builtin_bit_cast(half8,
            *(const short8*)&Bbase[(pi * 16 + r) * SKP + kk * 32 + kq * 8]);
        c0 = __builtin_amdgcn_mfma_f32_16x16x32_f16(afrag[0][kk], bfrag, c0, 0, 0, 0);
        c1 = __builtin_amdgcn_mfma_f32_16x16x32_f16(afrag[1][kk], bfrag, c1, 0, 0, 0);
      }
      // C layout (m89-verified, dtype-independent): col=lane&15, row=(lane>>4)*4+rr
      const int col = pi * 16 + (lane & 15);
      const int rb = (lane >> 4) * 4;
      #pragma unroll
      for (int rr = 0; rr < 4; ++rr) {
        Sbase[(rb + rr) * SSP + col]      = c0[rr];
        Sbase[(16 + rb + rr) * SSP + col] = c1[rr];
      }
    }
    __syncthreads();

    // online softmax + PV accumulate; thread handles 4 p's of its q-row
    {
      float sv0 = Sk[qrow * SSP + s8 * 4 + 0];
      float sv1 = Sk[qrow * SSP + s8 * 4 + 1];
      float sv2 = Sk[qrow * SSP + s8 * 4 + 2];
      float sv3 = Sk[qrow * SSP + s8 * 4 + 3];
      float tmax = fmaxf(fmaxf(fmaxf(sv0, sv1), fmaxf(sv2, sv3)), mx0);
      float sc = __expf(mx0 - tmax);
      l0 *= sc; a00 *= sc; a01 *= sc; a02 *= sc;
      float e0 = __expf(sv0 - tmax), e1 = __expf(sv1 - tmax);
      float e2 = __expf(sv2 - tmax), e3 = __expf(sv3 - tmax);
      l0 += e0 + e1 + e2 + e3;
      const float* V0 = &PVt[(s8 * 4) * CV];
      a00 += e0 * V0[0] + e1 * V0[3] + e2 * V0[6] + e3 * V0[9];
      a01 += e0 * V0[1] + e1 * V0[4] + e2 * V0[7] + e3 * V0[10];
      a02 += e0 * V0[2] + e1 * V0[5] + e2 * V0[8] + e3 * V0[11];
      mx0 = tmax;
    }
    {
      float sv0 = Sm[qrow * SSP + s8 * 4 + 0];
      float sv1 = Sm[qrow * SSP + s8 * 4 + 1];
      float sv2 = Sm[qrow * SSP + s8 * 4 + 2];
      float sv3 = Sm[qrow * SSP + s8 * 4 + 3];
      float tmax = fmaxf(fmaxf(fmaxf(sv0, sv1), fmaxf(sv2, sv3)), mx1);
      float sc = __expf(mx1 - tmax);
      l1 *= sc; a10 *= sc; a11 *= sc; a12 *= sc;
      float e0 = __expf(sv0 - tmax), e1 = __expf(sv1 - tmax);
      float e2 = __expf(sv2 - tmax), e3 = __expf(sv3 - tmax);
      l1 += e0 + e1 + e2 + e3;
      const float* V1 = &MVt[(s8 * 4) * CV];
      a10 += e0 * V1[0] + e1 * V1[3] + e2 * V1[6] + e3 * V1[9];
      a11 += e0 * V1[1] + e1 * V1[4] + e2 * V1[7] + e3 * V1[10];
      a12 += e0 * V1[2] + e1 * V1[5] + e2 * V1[8] + e3 * V1[11];
      mx1 = tmax;
    }
  }

  // merge the 8 per-thread partial softmax states of each q-row (lanes q*8+s)
  #pragma unroll
  for (int off = 1; off < 8; off <<= 1) {
    {
      float m2 = __shfl_xor(mx0, off);
      float l2 = __shfl_xor(l0, off);
      float b0s = __shfl_xor(a00, off);
      float b1s = __shfl_xor(a01, off);
      float b2s = __shfl_xor(a02, off);
      float mn = fmaxf(mx0, m2);
      float e1 = __expf(mx0 - mn), e2 = __expf(m2 - mn);
      l0 = l0 * e1 + l2 * e2;
      a00 = a00 * e1 + b0s * e2; a01 = a01 * e1 + b1s * e2; a02 = a02 * e1 + b2s * e2;
      mx0 = mn;
    }
    {
      float m2 = __shfl_xor(mx1, off);
      float l2 = __shfl_xor(l1, off);
      float b0s = __shfl_xor(a10, off);
      float b1s = __shfl_xor(a11, off);
      float b2s = __shfl_xor(a12, off);
      float mn = fmaxf(mx1, m2);
      float e1 = __expf(mx1 - mn), e2 = __expf(m2 - mn);
      l1 = l1 * e1 + l2 * e2;
      a10 = a10 * e1 + b0s * e2; a11 = a11 * e1 + b1s * e2; a12 = a12 * e1 + b2s * e2;
      mx1 = mn;
    }
  }

  if (s8 == 0) {
    const int q = q0 + qrow;
    const float ik = 1.0f / l0, im = 1.0f / l1;
    const int maskv = seq_mask[b * SEQ + step];
    float* ov = out + ((long)(b * STEPS + step) * HW + q) * CV;
    float* po = pv_out + ((long)lb * HW + q) * CV;
    const float* vr = v + ((long)(b * SEQ + step) * HW + q) * CV;
    float rk[3] = {a00, a01, a02};
    float rm[3] = {a10, a11, a12};
    #pragma unroll
    for (int c = 0; c < 3; ++c) {
      float rec = 0.9f * rk[c] * ik + 0.1f * rm[c] * im;  // COEF_MEMORY = 0.1
      ov[c] = rec;
      po[c] = maskv ? vr[c] : rec;  // prev_v carry fp32
    }
  }
}

extern "C" void kernel_launch(void* const* d_in, const int* in_sizes, int n_in,
                              void* d_out, int out_size, void* d_ws, size_t ws_size,
                              hipStream_t stream) {
  const float* k   = (const float*)d_in[0];
  const float* v   = (const float*)d_in[1];
  const float* att = (const float*)d_in[2];
  const int* seq_mask = (const int*)d_in[3];
  float* out = (float*)d_out;

  // per-batch footprint: m_k fp32 1MB + m_kh fp16 0.5MB + m_v/pvA/pvB 36KB
  const size_t MK_B  = (size_t)HW * CK * 4;   // 1,048,576
  const size_t MKH_B = (size_t)HW * CK * 2;   //   524,288
  const size_t SV_B  = (size_t)HW * CV * 4;   //    12,288
  const size_t PER_B = MK_B + MKH_B + 3 * SV_B;  // 1,609,728

  int nb = (int)(ws_size / PER_B);
  if (nb < 1) nb = 1;
  if (nb > BS) nb = BS;

  char* ws = (char*)d_ws;

  gt_copy<<<1440, 256, 0, stream>>>(v, out);

  for (int b0 = 0; b0 < BS; b0 += nb) {
    int nbp = (b0 + nb <= BS) ? nb : (BS - b0);
    float* m_k  = (float*)(ws + 0);
    u16*   m_kh = (u16*)(ws + (size_t)nb * MK_B);
    float* m_v  = (float*)(ws + (size_t)nb * (MK_B + MKH_B));
    float* pvA  = (float*)(ws + (size_t)nb * (MK_B + MKH_B + SV_B));
    float* pvB  = (float*)(ws + (size_t)nb * (MK_B + MKH_B + SV_B * 2));

    init_state<<<1024, 256, 0, stream>>>(v, m_k, m_v, pvA, b0, nbp);

    for (int i = 0; i < STEPS; ++i) {
      float* pin  = (i & 1) ? pvB : pvA;
      float* pout = (i & 1) ? pvA : pvB;
      update_state<<<dim3(nbp, 32), 256, 0, stream>>>(k, att, pin, m_k, m_kh, m_v, i, b0);
      attn_step<<<dim3(nbp, 32), 256, 0, stream>>>(k, v, seq_mask, m_kh, m_v,
                                                   pin, pout, out, i, b0);
    }
  }
}

// Round 5
// 832.544 us; speedup vs baseline: 1.6557x; 1.6557x over previous
//
#include <hip/hip_runtime.h>

// Problem: bs=8, seq=16, hw=32*32=1024, ck=256, cv=3, steps=seq-1=15
// Inputs fp32: k[8][16][1024][256], v[8][16][1024][3], attention[8][16][1024],
//              seq_mask int32[8][16].  Outputs fp32: out_v ++ gt (each 8x15x1024x3).
//
// R5 design: barrier-free attn. A-operand = p-rows (streamed fp16 from ws),
// B-operand = q-tile (registers). C-layout => softmax over p is in-register.
// k fp16 tiles ping-pong in ws (converted by prior step's update kernel).
// m_k EMA state fp16 (decaying rounding noise, ~1.3x the fp32+mirror scheme).
#define BS 8
#define SEQ 16
#define HW 1024
#define CK 256
#define CV 3
#define STEPS 15

#define SKP 264   // padded fp16 LDS row stride (256+8)

typedef unsigned short u16;
typedef _Float16 half8 __attribute__((ext_vector_type(8)));  // MFMA A/B frag
typedef float floatx4 __attribute__((ext_vector_type(4)));   // MFMA C/D frag

__device__ __forceinline__ u16 f2h(float f) {
  _Float16 h = (_Float16)f;
  return __builtin_bit_cast(unsigned short, h);
}
__device__ __forceinline__ float h2f(u16 u) {
  _Float16 h = __builtin_bit_cast(_Float16, u);
  return (float)h;
}

// ---- prep (once per pass): kh0 = fp16(k[:,0]), m_kh = 0, m_v = 0, pv = v[:,0] ----
__global__ __launch_bounds__(256) void prep(const float* __restrict__ k,
                                            const float* __restrict__ v,
                                            u16* __restrict__ kh0,
                                            u16* __restrict__ m_kh,
                                            float* __restrict__ m_v,
                                            float* __restrict__ pv,
                                            int b0, int nb) {
  long idx = (long)blockIdx.x * 256 + threadIdx.x;
  long stride = (long)gridDim.x * 256;
  const long HC8 = (long)HW * CK / 8;          // 32768 chunks per batch-tile
  const long nk8 = (long)nb * HC8;
  for (long i = idx; i < nk8; i += stride) {
    long lb = i / HC8, r = i - lb * HC8;
    const float* src = k + (long)(b0 + lb) * SEQ * HW * CK + r * 8;  // step-0 tile
    float4 a = *(const float4*)src;
    float4 b4 = *(const float4*)(src + 4);
    u16 t[8] = {f2h(a.x), f2h(a.y), f2h(a.z), f2h(a.w),
                f2h(b4.x), f2h(b4.y), f2h(b4.z), f2h(b4.w)};
    *(int4*)(kh0 + i * 8) = *(const int4*)t;
  }
  int4 z = {0, 0, 0, 0};
  for (long i = idx; i < nk8; i += stride) *(int4*)(m_kh + i * 8) = z;
  const long nv = (long)nb * HW * CV;
  for (long i = idx; i < nv; i += stride) {
    m_v[i] = 0.0f;
    long lb = i / (HW * CV), r = i - lb * (HW * CV);
    pv[i] = v[(long)(b0 + lb) * SEQ * HW * CV + r];
  }
}

// ---------------- gt = v[:,1:] (pure copy, fp32) ----------------
__global__ __launch_bounds__(256) void gt_copy(const float* __restrict__ v,
                                               float* __restrict__ out) {
  int idx = blockIdx.x * 256 + threadIdx.x;
  const int n = BS * STEPS * HW * CV;            // 368,640
  if (idx >= n) return;
  int b = idx / (STEPS * HW * CV);
  int r = idx - b * (STEPS * HW * CV);
  int i = r / (HW * CV);
  int rr = r - i * (HW * CV);
  out[n + idx] = v[(long)(b * SEQ + i + 1) * (HW * CV) + rr];
}

// --------- per-step: m_kh EMA (fp16 state, fp32 math), m_v, and
//           convert k[:, step+1] -> kh_next (for this and next step's attn) ---------
// grid (nb,32), 256 thr: thread (pl=tid>>3, s=tid&7) -> row pb*32+pl, cols [s*32, s*32+32)
__global__ __launch_bounds__(256) void update_state(
    const float* __restrict__ k, const float* __restrict__ att,
    const float* __restrict__ pv_in,
    const u16* __restrict__ kh_cur, u16* __restrict__ kh_next,
    u16* __restrict__ m_kh, float* __restrict__ m_v, int step, int b0)
{
  const int lb = blockIdx.x, b = b0 + lb, pb = blockIdx.y;
  const int tid = threadIdx.x;
  const int pl = tid >> 3, s = tid & 7;
  const int p = pb * 32 + pl;

  { // fp32 -> fp16 conversion of next step's k tile
    const float* src = k + ((long)(b * SEQ + step + 1) * HW + p) * CK + s * 32;
    u16* dst = kh_next + ((long)lb * HW + p) * CK + s * 32;
    #pragma unroll
    for (int c = 0; c < 32; c += 8) {
      float4 a = *(const float4*)(src + c);
      float4 b4 = *(const float4*)(src + c + 4);
      u16 t[8] = {f2h(a.x), f2h(a.y), f2h(a.z), f2h(a.w),
                  f2h(b4.x), f2h(b4.y), f2h(b4.z), f2h(b4.w)};
      *(int4*)(dst + c) = *(const int4*)t;
    }
  }

  float a = att[(long)(b * SEQ + step) * HW + p];
  float g = 1.0f / (1.0f + __expf(-a));
  float og = 1.0f - g;

  const u16* krow = kh_cur + ((long)lb * HW + p) * CK + s * 32;
  u16* mrow = m_kh + ((long)lb * HW + p) * CK + s * 32;
  #pragma unroll
  for (int c = 0; c < 32; c += 8) {
    int4 kr = *(const int4*)(krow + c);
    int4 mr = *(const int4*)(mrow + c);
    const u16* ku = (const u16*)&kr;
    const u16* mu = (const u16*)&mr;
    u16 nh[8];
    #pragma unroll
    for (int j = 0; j < 8; ++j)
      nh[j] = f2h(fmaf(g, h2f(ku[j]), og * h2f(mu[j])));
    *(int4*)(mrow + c) = *(const int4*)&nh[0];
  }

  if (s == 0) {  // m_v = g*prev_v + (1-g)*m_v
    long base = ((long)lb * HW + p) * CV;
    #pragma unroll
    for (int c = 0; c < CV; ++c)
      m_v[base + c] = fmaf(g, pv_in[base + c], og * m_v[base + c]);
  }
}

// --------- per-step fused dual-attention: barrier-free wave-autonomous ---------
// grid (nb, 32): block = (batch, 32 q-rows), 512 thr = 8 waves.
// Wave w owns p-range [w*128, (w+1)*128) as 4 chunks of 32.
// MFMA: A = p-rows (streamed), B = q-tile (regs). D[p][q]: lane q=lane&15(+16*qi),
// p-rows = (lane>>4)*4+reg -> online softmax over p is in-register.
__global__ __launch_bounds__(512, 2) void attn_step(
    const u16* __restrict__ kh_c, const u16* __restrict__ kh_n,
    const float* __restrict__ v, const int* __restrict__ seq_mask,
    const u16* __restrict__ m_kh, const float* __restrict__ m_v,
    const float* __restrict__ pv_in, float* __restrict__ pv_out,
    float* __restrict__ out, int step, int b0)
{
  __shared__ u16 Kq[32 * SKP];          // q-tile fp16 (16.9 KB)
  __shared__ float Mg[8][2][32][5];     // per-wave partial states (10.2 KB)

  const int lb = blockIdx.x, b = b0 + lb;
  const int q0 = blockIdx.y * 32;
  const int tid = threadIdx.x;
  const int w = tid >> 6, lane = tid & 63;
  const int r = lane & 15, rg = lane >> 4;

  const u16* Kn = kh_n + (long)lb * HW * CK;   // k[:, step+1] (q side)
  const u16* Kc = kh_c + (long)lb * HW * CK;   // k[:, step]   (p side)
  const u16* Mb = m_kh + (long)lb * HW * CK;   // m_k          (p side)

  { // stage q-tile: 1024 16B-chunks over 512 threads
    #pragma unroll
    for (int j = 0; j < 2; ++j) {
      int c = tid + j * 512;
      int row = c >> 5, off = (c & 31) * 8;
      *(int4*)&Kq[row * SKP + off] = *(const int4*)(Kn + (long)(q0 + row) * CK + off);
    }
  }
  __syncthreads();

  // B fragments (q-tile) held in registers: 2 q-subtiles x 8 k-steps
  half8 Bq[2][8];
  #pragma unroll
  for (int qi = 0; qi < 2; ++qi)
    #pragma unroll
    for (int kk = 0; kk < 8; ++kk)
      Bq[qi][kk] = *(const half8*)&Kq[(qi * 16 + r) * SKP + kk * 32 + rg * 8];

  // online state per (mat, qi): q-col = qi*16 + r, p-subset = this lane's rows
  float mx[2][2], l[2][2], acc[2][2][3];
  #pragma unroll
  for (int m = 0; m < 2; ++m)
    #pragma unroll
    for (int qi = 0; qi < 2; ++qi) {
      mx[m][qi] = -1e30f; l[m][qi] = 0.f;
      acc[m][qi][0] = acc[m][qi][1] = acc[m][qi][2] = 0.f;
    }

  const float* PV0 = pv_in + (long)lb * HW * CV;
  const float* PV1 = m_v + (long)lb * HW * CV;

  for (int pc = 0; pc < 4; ++pc) {
    const int p0 = w * 128 + pc * 32;
    #pragma unroll
    for (int mat = 0; mat < 2; ++mat) {
      const u16* Ab = mat ? Mb : Kc;
      const float* PV = mat ? PV1 : PV0;
      #pragma unroll
      for (int pi = 0; pi < 2; ++pi) {
        const int pr = p0 + pi * 16;
        // V values for this lane's 4 p-rows (broadcast across the 16 lanes of rg)
        float Vv[4][3];
        #pragma unroll
        for (int j = 0; j < 4; ++j) {
          const float* vp = PV + (long)(pr + rg * 4 + j) * CV;
          Vv[j][0] = vp[0]; Vv[j][1] = vp[1]; Vv[j][2] = vp[2];
        }
        // A fragments: 16 p-rows x 32-k per kk step
        half8 A[8];
        #pragma unroll
        for (int kk = 0; kk < 8; ++kk)
          A[kk] = *(const half8*)(Ab + (long)(pr + r) * CK + kk * 32 + rg * 8);
        floatx4 c0 = {0.f, 0.f, 0.f, 0.f}, c1 = {0.f, 0.f, 0.f, 0.f};
        #pragma unroll
        for (int kk = 0; kk < 8; ++kk) {
          c0 = __builtin_amdgcn_mfma_f32_16x16x32_f16(A[kk], Bq[0][kk], c0, 0, 0, 0);
          c1 = __builtin_amdgcn_mfma_f32_16x16x32_f16(A[kk], Bq[1][kk], c1, 0, 0, 0);
        }
        // absorb 4 p-values per qi into online state
        #pragma unroll
        for (int qi = 0; qi < 2; ++qi) {
          floatx4 cc = qi ? c1 : c0;
          float tmax = fmaxf(fmaxf(cc[0], cc[1]), fmaxf(cc[2], cc[3]));
          tmax = fmaxf(tmax, mx[mat][qi]);
          float sc = __expf(mx[mat][qi] - tmax);
          l[mat][qi] *= sc;
          acc[mat][qi][0] *= sc; acc[mat][qi][1] *= sc; acc[mat][qi][2] *= sc;
          #pragma unroll
          for (int j = 0; j < 4; ++j) {
            float e = __expf(cc[j] - tmax);
            l[mat][qi] += e;
            acc[mat][qi][0] = fmaf(e, Vv[j][0], acc[mat][qi][0]);
            acc[mat][qi][1] = fmaf(e, Vv[j][1], acc[mat][qi][1]);
            acc[mat][qi][2] = fmaf(e, Vv[j][2], acc[mat][qi][2]);
          }
          mx[mat][qi] = tmax;
        }
      }
    }
  }

  // merge the 4 rowgroup partials (lanes r, r+16, r+32, r+48) via shuffle
  #pragma unroll
  for (int off = 16; off <= 32; off <<= 1) {
    #pragma unroll
    for (int m = 0; m < 2; ++m)
      #pragma unroll
      for (int qi = 0; qi < 2; ++qi) {
        float m2 = __shfl_xor(mx[m][qi], off);
        float l2 = __shfl_xor(l[m][qi], off);
        float b0s = __shfl_xor(acc[m][qi][0], off);
        float b1s = __shfl_xor(acc[m][qi][1], off);
        float b2s = __shfl_xor(acc[m][qi][2], off);
        float mn = fmaxf(mx[m][qi], m2);
        float e1 = __expf(mx[m][qi] - mn), e2 = __expf(m2 - mn);
        l[m][qi] = l[m][qi] * e1 + l2 * e2;
        acc[m][qi][0] = acc[m][qi][0] * e1 + b0s * e2;
        acc[m][qi][1] = acc[m][qi][1] * e1 + b1s * e2;
        acc[m][qi][2] = acc[m][qi][2] * e1 + b2s * e2;
        mx[m][qi] = mn;
      }
  }
  if (rg == 0) {
    #pragma unroll
    for (int m = 0; m < 2; ++m)
      #pragma unroll
      for (int qi = 0; qi < 2; ++qi) {
        float* d = Mg[w][m][qi * 16 + r];
        d[0] = mx[m][qi]; d[1] = l[m][qi];
        d[2] = acc[m][qi][0]; d[3] = acc[m][qi][1]; d[4] = acc[m][qi][2];
      }
  }
  __syncthreads();

  // final cross-wave merge + output: one thread per q-row
  if (tid < 32) {
    const int q = tid;
    float res[2][3];
    #pragma unroll
    for (int m = 0; m < 2; ++m) {
      float M = -1e30f, L = 0.f, A0 = 0.f, A1 = 0.f, A2 = 0.f;
      #pragma unroll
      for (int ww = 0; ww < 8; ++ww) {
        const float* d = Mg[ww][m][q];
        float mn = fmaxf(M, d[0]);
        float e1 = __expf(M - mn), e2 = __expf(d[0] - mn);
        L = L * e1 + d[1] * e2;
        A0 = A0 * e1 + d[2] * e2;
        A1 = A1 * e1 + d[3] * e2;
        A2 = A2 * e1 + d[4] * e2;
        M = mn;
      }
      float iL = 1.0f / L;
      res[m][0] = A0 * iL; res[m][1] = A1 * iL; res[m][2] = A2 * iL;
    }
    const int maskv = seq_mask[b * SEQ + step];
    const int qg = q0 + q;
    float* ov = out + ((long)(b * STEPS + step) * HW + qg) * CV;
    float* po = pv_out + ((long)lb * HW + qg) * CV;
    const float* vr = v + ((long)(b * SEQ + step) * HW + qg) * CV;
    #pragma unroll
    for (int c = 0; c < CV; ++c) {
      float rec = 0.9f * res[0][c] + 0.1f * res[1][c];  // COEF_MEMORY = 0.1
      ov[c] = rec;
      po[c] = maskv ? vr[c] : rec;
    }
  }
}

extern "C" void kernel_launch(void* const* d_in, const int* in_sizes, int n_in,
                              void* d_out, int out_size, void* d_ws, size_t ws_size,
                              hipStream_t stream) {
  const float* k   = (const float*)d_in[0];
  const float* v   = (const float*)d_in[1];
  const float* att = (const float*)d_in[2];
  const int* seq_mask = (const int*)d_in[3];
  float* out = (float*)d_out;

  // per-batch footprint (matches round-4's proven 1,609,728 B/batch):
  // khA 512KB + khB 512KB + m_kh 512KB + m_v/pvA/pvB 3x12KB
  const size_t KHT_B = (size_t)HW * CK * 2;   // 524,288
  const size_t SV_B  = (size_t)HW * CV * 4;   //  12,288
  const size_t PER_B = 3 * KHT_B + 3 * SV_B;  // 1,609,728

  int nb = (int)(ws_size / PER_B);
  if (nb < 1) nb = 1;
  if (nb > BS) nb = BS;

  char* ws = (char*)d_ws;

  gt_copy<<<1440, 256, 0, stream>>>(v, out);

  for (int b0 = 0; b0 < BS; b0 += nb) {
    int nbp = (b0 + nb <= BS) ? nb : (BS - b0);
    u16*   khA  = (u16*)(ws + 0);
    u16*   khB  = (u16*)(ws + (size_t)nb * KHT_B);
    u16*   m_kh = (u16*)(ws + (size_t)nb * KHT_B * 2);
    float* m_v  = (float*)(ws + (size_t)nb * KHT_B * 3);
    float* pvA  = (float*)(ws + (size_t)nb * (KHT_B * 3 + SV_B));
    float* pvB  = (float*)(ws + (size_t)nb * (KHT_B * 3 + SV_B * 2));

    prep<<<1024, 256, 0, stream>>>(k, v, khA, m_kh, m_v, pvA, b0, nbp);

    for (int i = 0; i < STEPS; ++i) {
      u16* khc = (i & 1) ? khB : khA;   // holds k[:, i]
      u16* khn = (i & 1) ? khA : khB;   // update writes k[:, i+1] here
      float* pin  = (i & 1) ? pvB : pvA;
      float* pout = (i & 1) ? pvA : pvB;
      update_state<<<dim3(nbp, 32), 256, 0, stream>>>(k, att, pin, khc, khn,
                                                      m_kh, m_v, i, b0);
      attn_step<<<dim3(nbp, 32), 512, 0, stream>>>(khc, khn, v, seq_mask,
                                                   m_kh, m_v, pin, pout, out, i, b0);
    }
  }
}